// Round 6
// baseline (253.509 us; speedup 1.0000x reference)
//
#include <hip/hip_runtime.h>
#include <math.h>

typedef __attribute__((ext_vector_type(8))) short s8v;   // 8 x bf16 (4 VGPRs) — MFMA A/B frag
typedef __attribute__((ext_vector_type(4))) float f4v;   // 4 x fp32 — MFMA C/D frag
typedef unsigned short u16;
typedef unsigned int u32;

constexpr int Bsz = 4, NQ = 4096, NC = 1024, NH = 8, DH = 64, DI = 512, DC = 768;

__device__ __forceinline__ u16 f2bf(float f) {
  union { float f; u32 u; } v; v.f = f;
  u32 r = v.u + 0x7fff + ((v.u >> 16) & 1);  // RNE
  return (u16)(r >> 16);
}

// pack two f32 -> two bf16 in one dword (round-half-up)
__device__ __forceinline__ u32 pack2(float a, float b) {
  union { float f; u32 u; } ua, ub; ua.f = a; ub.f = b;
#if __has_builtin(__builtin_amdgcn_perm)
  return __builtin_amdgcn_perm(ub.u + 0x8000u, ua.u + 0x8000u, 0x07060302u);
#else
  return ((ub.u + 0x8000u) & 0xffff0000u) | ((ua.u + 0x8000u) >> 16);
#endif
}

#if __has_builtin(__builtin_amdgcn_exp2f)
#define EXP2(x) __builtin_amdgcn_exp2f(x)
#else
#define EXP2(x) exp2f(x)
#endif

// async global->LDS, 16B per lane (m97 pattern)
__device__ __forceinline__ void g2l16(const void* g, void* l) {
  __builtin_amdgcn_global_load_lds((const __attribute__((address_space(1))) u32*)g,
                                   (__attribute__((address_space(3))) u32*)l, 16, 0, 0);
}

// ---------------- prep: casts + all weight transposes in one launch ----------------
__global__ __launch_bounds__(256) void prep(const float* __restrict__ x, const float* __restrict__ ctx,
                                            const float* __restrict__ Wq, const float* __restrict__ Wk,
                                            const float* __restrict__ Wv, const float* __restrict__ Wo,
                                            u16* __restrict__ xb, u16* __restrict__ cb,
                                            u16* __restrict__ wqT, u16* __restrict__ wkvT,
                                            u16* __restrict__ woT) {
  int bx = blockIdx.x;
  if (bx < 11264) {                       // cast path: x then ctx, float4-vectorized
    const int NX4 = Bsz * NQ * DI / 4;    // 2097152
    const int NC4 = Bsz * NC * DC / 4;    // 786432
    int i = bx * 256 + threadIdx.x;
    float4 v; u16* dst; int j;
    if (i < NX4) { v = ((const float4*)x)[i]; dst = xb; j = i; }
    else { j = i - NX4; if (j >= NC4) return; v = ((const float4*)ctx)[j]; dst = cb; }
    ushort4 o; o.x = f2bf(v.x); o.y = f2bf(v.y); o.z = f2bf(v.z); o.w = f2bf(v.w);
    ((ushort4*)dst)[j] = o;
    return;
  }
  // weight transpose path: W[K][N] fp32 -> W^T[N][K] bf16
  int idx = bx - 11264;                   // [0,384)
  int z = idx / 96, rem = idx % 96, kx = rem % 12, ny = rem / 12;
  const float* src; u16* dst; int K; const int N = 512;
  if (z == 0)      { src = Wq; dst = wqT;              K = 512; }
  else if (z == 1) { src = Wk; dst = wkvT;             K = 768; }
  else if (z == 2) { src = Wv; dst = wkvT + 512 * 768; K = 768; }
  else             { src = Wo; dst = woT;              K = 512; }
  int k0 = kx * 64, n0 = ny * 64;
  if (k0 >= K) return;
  __shared__ u16 t[64][65];
  int tid = threadIdx.x, jr = tid & 63, ir = tid >> 6;
  for (int it = 0; it < 16; ++it) { int i = it * 4 + ir; t[i][jr] = f2bf(src[(size_t)(k0 + i) * N + n0 + jr]); }
  __syncthreads();
  for (int it = 0; it < 16; ++it) { int i = it * 4 + ir; dst[(size_t)(n0 + i) * K + k0 + jr] = t[jr][i]; }
}

// ---------------- shared GEMM body: 128x128 tile, BK=32, dbuf global_load_lds staging --------
// MODE 0: bf16 C, row-stride N, scaled.  MODE 1: fp32 C + bias.  MODE 2: KV special —
// cols <512 are K-projection (bf16 -> Kb stride 512); cols >=512 are V-projection written
// directly transposed+key-permuted into Vt[(b*8+h)][d][t']
// (p' = (a&32) + ((a&15)>>2)*8 + ((a>>4)&1)*4 + (a&3)).
template <int MODE>
__device__ __forceinline__ void gemm_body(const u16* __restrict__ A, const u16* __restrict__ Bt,
                                          void* __restrict__ C0, void* __restrict__ C1,
                                          const float* __restrict__ bias, int N, int K,
                                          float oscale, int nbx, int mby,
                                          u16* Al, u16* Bl) {   // Al/Bl: [2][128][32]
  int mb = mby * 128, nb = nbx * 128;
  int tid = threadIdx.x, lane = tid & 63, quad = lane >> 4, l16 = lane & 15, wave = tid >> 6;
  int wm = (wave >> 1) * 64, wn = (wave & 1) * 64;
  f4v acc[4][4];
  #pragma unroll
  for (int i = 0; i < 4; i++)
    #pragma unroll
    for (int j = 0; j < 4; j++) acc[i][j] = (f4v){0.f, 0.f, 0.f, 0.f};

  int r0 = tid >> 2, c0 = (tid & 3) * 8;
  const u16* Ap0 = A + (size_t)(mb + r0) * K + c0;
  const u16* Ap1 = A + (size_t)(mb + r0 + 64) * K + c0;
  const u16* Bp0 = Bt + (size_t)(nb + r0) * K + c0;
  const u16* Bp1 = Bt + (size_t)(nb + r0 + 64) * K + c0;

#define GSTAGE(k0, buf) do { \
    u16* al_ = Al + (buf) * 4096; u16* bl_ = Bl + (buf) * 4096; \
    g2l16(Ap0 + (k0), al_ + tid * 8); \
    g2l16(Ap1 + (k0), al_ + (tid + 256) * 8); \
    g2l16(Bp0 + (k0), bl_ + tid * 8); \
    g2l16(Bp1 + (k0), bl_ + (tid + 256) * 8); } while (0)

  GSTAGE(0, 0);
  int nk = K >> 5;
  for (int t = 0; t < nk; ++t) {
    __syncthreads();                         // drains prefetch (vmcnt) + protects dbuf reuse
    if (t + 1 < nk) GSTAGE((t + 1) * 32, (t + 1) & 1);
    const u16* al = Al + (t & 1) * 4096;
    const u16* bl = Bl + (t & 1) * 4096;
    s8v af[4], bfr[4];
    #pragma unroll
    for (int i = 0; i < 4; i++) af[i] = *(const s8v*)(al + (wm + i * 16 + l16) * 32 + quad * 8);
    #pragma unroll
    for (int j = 0; j < 4; j++) bfr[j] = *(const s8v*)(bl + (wn + j * 16 + l16) * 32 + quad * 8);
    #pragma unroll
    for (int i = 0; i < 4; i++)
      #pragma unroll
      for (int j = 0; j < 4; j++)
        acc[i][j] = __builtin_amdgcn_mfma_f32_16x16x32_bf16(af[i], bfr[j], acc[i][j], 0, 0, 0);
  }
#undef GSTAGE
  #pragma unroll
  for (int i = 0; i < 4; i++) {
    int rbase = mb + wm + i * 16 + quad * 4;
    #pragma unroll
    for (int j = 0; j < 4; j++) {
      int col = nb + wn + j * 16 + l16;
      if (MODE == 0) {
        u16* Cb = (u16*)C0;
        #pragma unroll
        for (int r = 0; r < 4; r++) Cb[(size_t)(rbase + r) * N + col] = f2bf(acc[i][j][r] * oscale);
      } else if (MODE == 1) {
        float* Cf = (float*)C0;
        #pragma unroll
        for (int r = 0; r < 4; r++) Cf[(size_t)(rbase + r) * N + col] = acc[i][j][r] + bias[col];
      } else {
        if (col < 512) {                  // K projection -> Kb [b*NC+t][512]
          u16* Kb = (u16*)C0;
          #pragma unroll
          for (int r = 0; r < 4; r++) Kb[(size_t)(rbase + r) * 512 + col] = f2bf(acc[i][j][r]);
        } else {                          // V projection -> Vt, transposed + key-permuted
          u16* Vt = (u16*)C1;
          int hd = col - 512, h = hd >> 6, d = hd & 63;
          int bb = rbase >> 10, tl = rbase & 1023;
          int tbase = tl & ~63, a0 = tl & 63;          // a0 = quad*4-aligned key-local idx
          int pb = (a0 & 32) + ((a0 & 15) >> 2) * 8 + (((a0 >> 4) & 1) << 2);
          uint2 ov;
          ov.x = pack2(acc[i][j][0], acc[i][j][1]);
          ov.y = pack2(acc[i][j][2], acc[i][j][3]);
          *(uint2*)(Vt + ((size_t)(bb * NH + h) * DH + d) * NC + tbase + pb) = ov;
        }
      }
    }
  }
}

// ---------------- fused Q-proj + KV-proj (768 blocks = 3/CU) ----------------
__global__ __launch_bounds__(256, 3) void proj_all(const u16* __restrict__ xb, const u16* __restrict__ cb,
                                                   const u16* __restrict__ wqT, const u16* __restrict__ wkvT,
                                                   u16* __restrict__ Qb, u16* __restrict__ Kb,
                                                   u16* __restrict__ Vtb, float qscale) {
  __shared__ alignas(16) u16 Al[2][128][32];
  __shared__ alignas(16) u16 Bl[2][128][32];
  int bx = blockIdx.x;
  if (bx < 512) {  // Q projection: M=16384, N=512, K=512
    gemm_body<0>(xb, wqT, Qb, nullptr, nullptr, 512, 512, qscale, bx & 3, bx >> 2,
                 (u16*)Al, (u16*)Bl);
  } else {         // KV projection: M=4096, N=1024, K=768; K cols -> Kb, V cols -> Vt
    int bi = bx - 512;
    gemm_body<2>(cb, wkvT, Kb, Vtb, nullptr, 1024, 768, 1.0f, bi & 7, bi >> 3,
                 (u16*)Al, (u16*)Bl);
  }
}

// ---------------- output projection (fp32 out + bias) ----------------
__global__ __launch_bounds__(256, 2) void outproj(const u16* __restrict__ Ob, const u16* __restrict__ woT,
                                                  float* __restrict__ out, const float* __restrict__ bo) {
  __shared__ alignas(16) u16 Al[2][128][32];
  __shared__ alignas(16) u16 Bl[2][128][32];
  gemm_body<1>(Ob, woT, out, nullptr, bo, 512, 512, 1.0f, blockIdx.x, blockIdx.y,
               (u16*)Al, (u16*)Bl);
}

// ---------------- flash cross-attention: 32-key tiles, 16 KB LDS, 8 blocks/CU ----------------
// S^T = K·Q^T; S^T C-layout packs in-register into the PV B-frag; V pre-permuted to match.
// O^T = V^T·P^T in C-layout (d contiguous per lane -> b64 stores).
// 128-thread blocks (2 waves x 64q), grid 1024; 16 KB LDS -> 8 blocks/CU = 4 waves/SIMD.
// K-tile keeps XOR-chunk swizzle (8 chunks/row); V-tile (4 chunks/row) is bank-balanced as-is.
__global__ __launch_bounds__(128, 4) void attn(const u16* __restrict__ Q, const u16* __restrict__ Kb,
                                               const u16* __restrict__ Vt, u16* __restrict__ O) {
  __shared__ alignas(16) u16 Kl[2][32][64];   // 8 KB
  __shared__ alignas(16) u16 Vl[2][64][32];   // 8 KB
  int qt = blockIdx.x, h = blockIdx.y, b = blockIdx.z;
  int tid = threadIdx.x, wave = tid >> 6, lane = tid & 63, quad = lane >> 4, l16 = lane & 15;
  int q0 = qt * 128 + wave * 64;
  int x7 = l16 & 7;

  // K staging: 256 chunks/tile; seg = tid + it*128 -> row=(tid>>3)+16*it, LDS chunk=tid&7,
  // global chunk=(tid&7)^(row&7) (row&7 invariant across it). V: row=(tid>>2)+32*it, chunk=tid&3.
  int kr = tid >> 3, kc = (tid & 7) ^ (kr & 7);
  const u16* kg = Kb + ((size_t)b * NC + kr) * 512 + h * DH + kc * 8;
  int vr = tid >> 2, vc = tid & 3;
  const u16* vg = Vt + ((size_t)(b * NH + h) * DH + vr) * NC + vc * 8;

#define ASTAGE(kt, buf) do { \
    const u16* kg_ = kg + (size_t)(kt) * 32 * 512; \
    const u16* vg_ = vg + (kt) * 32; \
    u16* kl_ = (u16*)Kl + (buf) * 2048; u16* vl_ = (u16*)Vl + (buf) * 2048; \
    g2l16(kg_,            kl_ + tid * 8); \
    g2l16(kg_ + 16 * 512, kl_ + (tid + 128) * 8); \
    g2l16(vg_,            vl_ + tid * 8); \
    g2l16(vg_ + 32 * NC,  vl_ + (tid + 128) * 8); } while (0)

  // Q B-frags (B[k=quad*8+j][n=l16]), in regs for the whole kernel
  s8v aq[4][2];
  {
    const u16* Qp = Q + ((size_t)b * NQ + q0 + l16) * DI + h * DH + quad * 8;
    #pragma unroll
    for (int n = 0; n < 4; n++) {
      aq[n][0] = *(const s8v*)(Qp + (size_t)n * 16 * DI);
      aq[n][1] = *(const s8v*)(Qp + (size_t)n * 16 * DI + 32);
    }
  }
  f4v oacc[4][4];
  float lsum[4] = {0.f, 0.f, 0.f, 0.f};
  #pragma unroll
  for (int d = 0; d < 4; d++)
    #pragma unroll
    for (int n = 0; n < 4; n++) oacc[d][n] = (f4v){0.f, 0.f, 0.f, 0.f};

  ASTAGE(0, 0);
  for (int kt = 0; kt < NC / 32; ++kt) {
    int buf = kt & 1;
    __syncthreads();                       // drains prefetch; orders dbuf reuse
    if (kt + 1 < NC / 32) ASTAGE(kt + 1, buf ^ 1);
    const u16* kb = (const u16*)Kl + buf * 2048;
    const u16* vb = (const u16*)Vl + buf * 2048;

    // S^T = K·Q^T for 32 keys (two 16-key m-subtiles), 16 MFMAs
    f4v S[2][4];
    #pragma unroll
    for (int mi = 0; mi < 2; mi++)
      #pragma unroll
      for (int n = 0; n < 4; n++) S[mi][n] = (f4v){0.f, 0.f, 0.f, 0.f};
    #pragma unroll
    for (int cd = 0; cd < 2; cd++) {       // dh chunk
      int ch = ((4 * cd + quad) ^ x7) * 8;
      s8v kf0 = *(const s8v*)(kb + l16 * 64 + ch);
      s8v kf1 = *(const s8v*)(kb + (l16 + 16) * 64 + ch);
      #pragma unroll
      for (int n = 0; n < 4; n++) {
        S[0][n] = __builtin_amdgcn_mfma_f32_16x16x32_bf16(kf0, aq[n][cd], S[0][n], 0, 0, 0);
        S[1][n] = __builtin_amdgcn_mfma_f32_16x16x32_bf16(kf1, aq[n][cd], S[1][n], 0, 0, 0);
      }
    }
    // exp2 + in-register pack into PV B-frag + row-sum accumulation
    s8v pf[4];
    #pragma unroll
    for (int n = 0; n < 4; n++) {
      float p00 = EXP2(S[0][n][0]), p01 = EXP2(S[0][n][1]), p02 = EXP2(S[0][n][2]), p03 = EXP2(S[0][n][3]);
      float p10 = EXP2(S[1][n][0]), p11 = EXP2(S[1][n][1]), p12 = EXP2(S[1][n][2]), p13 = EXP2(S[1][n][3]);
      lsum[n] += (p00 + p01) + (p02 + p03) + (p10 + p11) + (p12 + p13);
      union { u32 d[4]; s8v v; } u;
      u.d[0] = pack2(p00, p01); u.d[1] = pack2(p02, p03);
      u.d[2] = pack2(p10, p11); u.d[3] = pack2(p12, p13);
      pf[n] = u.v;
    }
    // O^T += V^T P^T, 16 MFMAs
    #pragma unroll
    for (int d = 0; d < 4; d++) {
      s8v vf = *(const s8v*)(vb + (d * 16 + l16) * 32 + quad * 8);
      #pragma unroll
      for (int n = 0; n < 4; n++)
        oacc[d][n] = __builtin_amdgcn_mfma_f32_16x16x32_bf16(vf, pf[n], oacc[d][n], 0, 0, 0);
    }
  }
#undef ASTAGE

  // reduce row sums across the 4 quads holding the same q (=l16 group)
  float inv[4];
  #pragma unroll
  for (int n = 0; n < 4; n++) {
    float s = lsum[n];
    s += __shfl_xor(s, 16); s += __shfl_xor(s, 32);
    inv[n] = 1.0f / s;
  }
  // write O[b][q][h*64+d]: lane holds 4 contiguous d per (dsub, n) -> b64 stores
  #pragma unroll
  for (int d = 0; d < 4; d++)
    #pragma unroll
    for (int n = 0; n < 4; n++) {
      int q = q0 + n * 16 + l16;
      uint2 ov;
      ov.x = pack2(oacc[d][n][0] * inv[n], oacc[d][n][1] * inv[n]);
      ov.y = pack2(oacc[d][n][2] * inv[n], oacc[d][n][3] * inv[n]);
      *(uint2*)(O + ((size_t)b * NQ + q) * DI + h * DH + d * 16 + quad * 4) = ov;
    }
}

extern "C" void kernel_launch(void* const* d_in, const int* in_sizes, int n_in,
                              void* d_out, int out_size, void* d_ws, size_t ws_size,
                              hipStream_t stream) {
  const float* x   = (const float*)d_in[0];
  const float* ctx = (const float*)d_in[1];
  const float* Wq  = (const float*)d_in[2];
  const float* Wk  = (const float*)d_in[3];
  const float* Wv  = (const float*)d_in[4];
  const float* Wo  = (const float*)d_in[5];
  const float* bo  = (const float*)d_in[6];
  float* out = (float*)d_out;

  u16* w    = (u16*)d_ws;                // workspace layout (bf16 elems)
  u16* xb   = w;                         // 8388608
  u16* cb   = xb   + 8388608;            // 3145728
  u16* wqT  = cb   + 3145728;            // 262144
  u16* wkvT = wqT  + 262144;             // 786432 (Wk^T rows 0-511, Wv^T rows 512-1023)
  u16* woT  = wkvT + 786432;             // 262144
  u16* Qb   = woT  + 262144;             // 8388608 (pre-scaled by 0.125*log2e)
  u16* Kbuf = Qb   + 8388608;            // 2097152 ([b*1024+t][512])
  u16* Vtb  = Kbuf + 2097152;            // 2097152 (key-permuted V^T)
  u16* Ob   = Vtb  + 2097152;            // 8388608

  const float qscale = 0.125f * 1.44269504f;  // softmax scale + log2(e) folded into Q

  prep<<<11648, 256, 0, stream>>>(x, ctx, Wq, Wk, Wv, Wo, xb, cb, wqT, wkvT, woT);
  proj_all<<<768, 256, 0, stream>>>(xb, cb, wqT, wkvT, Qb, Kbuf, Vtb, qscale);
  attn<<<dim3(32, 8, 4), 128, 0, stream>>>(Qb, Kbuf, Vtb, Ob);
  outproj<<<dim3(4, 128), 256, 0, stream>>>(Ob, woT, out, bo);
}

// Round 7
// 192.060 us; speedup vs baseline: 1.3199x; 1.3199x over previous
//
#include <hip/hip_runtime.h>
#include <math.h>

typedef __attribute__((ext_vector_type(8))) short s8v;   // 8 x bf16 (4 VGPRs) — MFMA A/B frag
typedef __attribute__((ext_vector_type(4))) float f4v;   // 4 x fp32 — MFMA C/D frag
typedef unsigned short u16;
typedef unsigned int u32;

constexpr int Bsz = 4, NQ = 4096, NC = 1024, NH = 8, DH = 64, DI = 512, DC = 768;

__device__ __forceinline__ u16 f2bf(float f) {
  union { float f; u32 u; } v; v.f = f;
  u32 r = v.u + 0x7fff + ((v.u >> 16) & 1);  // RNE
  return (u16)(r >> 16);
}

// pack two f32 -> two bf16 in one dword (round-half-up)
__device__ __forceinline__ u32 pack2(float a, float b) {
  union { float f; u32 u; } ua, ub; ua.f = a; ub.f = b;
#if __has_builtin(__builtin_amdgcn_perm)
  return __builtin_amdgcn_perm(ub.u + 0x8000u, ua.u + 0x8000u, 0x07060302u);
#else
  return ((ub.u + 0x8000u) & 0xffff0000u) | ((ua.u + 0x8000u) >> 16);
#endif
}

#if __has_builtin(__builtin_amdgcn_exp2f)
#define EXP2(x) __builtin_amdgcn_exp2f(x)
#else
#define EXP2(x) exp2f(x)
#endif

// async global->LDS, 16B per lane (m97 pattern)
__device__ __forceinline__ void g2l16(const void* g, void* l) {
  __builtin_amdgcn_global_load_lds((const __attribute__((address_space(1))) u32*)g,
                                   (__attribute__((address_space(3))) u32*)l, 16, 0, 0);
}

// ---------------- prep: casts + all weight transposes in one launch ----------------
__global__ __launch_bounds__(256) void prep(const float* __restrict__ x, const float* __restrict__ ctx,
                                            const float* __restrict__ Wq, const float* __restrict__ Wk,
                                            const float* __restrict__ Wv, const float* __restrict__ Wo,
                                            u16* __restrict__ xb, u16* __restrict__ cb,
                                            u16* __restrict__ wqT, u16* __restrict__ wkvT,
                                            u16* __restrict__ woT) {
  int bx = blockIdx.x;
  if (bx < 11264) {                       // cast path: x then ctx, float4-vectorized
    const int NX4 = Bsz * NQ * DI / 4;    // 2097152
    const int NC4 = Bsz * NC * DC / 4;    // 786432
    int i = bx * 256 + threadIdx.x;
    float4 v; u16* dst; int j;
    if (i < NX4) { v = ((const float4*)x)[i]; dst = xb; j = i; }
    else { j = i - NX4; if (j >= NC4) return; v = ((const float4*)ctx)[j]; dst = cb; }
    ushort4 o; o.x = f2bf(v.x); o.y = f2bf(v.y); o.z = f2bf(v.z); o.w = f2bf(v.w);
    ((ushort4*)dst)[j] = o;
    return;
  }
  // weight transpose path: W[K][N] fp32 -> W^T[N][K] bf16
  int idx = bx - 11264;                   // [0,384)
  int z = idx / 96, rem = idx % 96, kx = rem % 12, ny = rem / 12;
  const float* src; u16* dst; int K; const int N = 512;
  if (z == 0)      { src = Wq; dst = wqT;              K = 512; }
  else if (z == 1) { src = Wk; dst = wkvT;             K = 768; }
  else if (z == 2) { src = Wv; dst = wkvT + 512 * 768; K = 768; }
  else             { src = Wo; dst = woT;              K = 512; }
  int k0 = kx * 64, n0 = ny * 64;
  if (k0 >= K) return;
  __shared__ u16 t[64][65];
  int tid = threadIdx.x, jr = tid & 63, ir = tid >> 6;
  for (int it = 0; it < 16; ++it) { int i = it * 4 + ir; t[i][jr] = f2bf(src[(size_t)(k0 + i) * N + n0 + jr]); }
  __syncthreads();
  for (int it = 0; it < 16; ++it) { int i = it * 4 + ir; dst[(size_t)(n0 + i) * K + k0 + jr] = t[jr][i]; }
}

// ---------------- shared GEMM body: 128x128 tile, BK=32, dbuf global_load_lds staging --------
// MODE 0: bf16 C, row-stride N, scaled.  MODE 1: fp32 C + bias.  MODE 2: KV special —
// cols <512 are K-projection (bf16 -> Kb stride 512); cols >=512 are V-projection written
// directly transposed+key-permuted into Vt[(b*8+h)][d][t']
// (p' = (a&32) + ((a&15)>>2)*8 + ((a>>4)&1)*4 + (a&3)).
template <int MODE>
__device__ __forceinline__ void gemm_body(const u16* __restrict__ A, const u16* __restrict__ Bt,
                                          void* __restrict__ C0, void* __restrict__ C1,
                                          const float* __restrict__ bias, int N, int K,
                                          float oscale, int nbx, int mby,
                                          u16* Al, u16* Bl) {   // Al/Bl: [2][128][32]
  int mb = mby * 128, nb = nbx * 128;
  int tid = threadIdx.x, lane = tid & 63, quad = lane >> 4, l16 = lane & 15, wave = tid >> 6;
  int wm = (wave >> 1) * 64, wn = (wave & 1) * 64;
  f4v acc[4][4];
  #pragma unroll
  for (int i = 0; i < 4; i++)
    #pragma unroll
    for (int j = 0; j < 4; j++) acc[i][j] = (f4v){0.f, 0.f, 0.f, 0.f};

  int r0 = tid >> 2, c0 = (tid & 3) * 8;
  const u16* Ap0 = A + (size_t)(mb + r0) * K + c0;
  const u16* Ap1 = A + (size_t)(mb + r0 + 64) * K + c0;
  const u16* Bp0 = Bt + (size_t)(nb + r0) * K + c0;
  const u16* Bp1 = Bt + (size_t)(nb + r0 + 64) * K + c0;

#define GSTAGE(k0, buf) do { \
    u16* al_ = Al + (buf) * 4096; u16* bl_ = Bl + (buf) * 4096; \
    g2l16(Ap0 + (k0), al_ + tid * 8); \
    g2l16(Ap1 + (k0), al_ + (tid + 256) * 8); \
    g2l16(Bp0 + (k0), bl_ + tid * 8); \
    g2l16(Bp1 + (k0), bl_ + (tid + 256) * 8); } while (0)

  GSTAGE(0, 0);
  int nk = K >> 5;
  for (int t = 0; t < nk; ++t) {
    __syncthreads();                         // drains prefetch (vmcnt) + protects dbuf reuse
    if (t + 1 < nk) GSTAGE((t + 1) * 32, (t + 1) & 1);
    const u16* al = Al + (t & 1) * 4096;
    const u16* bl = Bl + (t & 1) * 4096;
    s8v af[4], bfr[4];
    #pragma unroll
    for (int i = 0; i < 4; i++) af[i] = *(const s8v*)(al + (wm + i * 16 + l16) * 32 + quad * 8);
    #pragma unroll
    for (int j = 0; j < 4; j++) bfr[j] = *(const s8v*)(bl + (wn + j * 16 + l16) * 32 + quad * 8);
    #pragma unroll
    for (int i = 0; i < 4; i++)
      #pragma unroll
      for (int j = 0; j < 4; j++)
        acc[i][j] = __builtin_amdgcn_mfma_f32_16x16x32_bf16(af[i], bfr[j], acc[i][j], 0, 0, 0);
  }
#undef GSTAGE
  #pragma unroll
  for (int i = 0; i < 4; i++) {
    int rbase = mb + wm + i * 16 + quad * 4;
    #pragma unroll
    for (int j = 0; j < 4; j++) {
      int col = nb + wn + j * 16 + l16;
      if (MODE == 0) {
        u16* Cb = (u16*)C0;
        #pragma unroll
        for (int r = 0; r < 4; r++) Cb[(size_t)(rbase + r) * N + col] = f2bf(acc[i][j][r] * oscale);
      } else if (MODE == 1) {
        float* Cf = (float*)C0;
        #pragma unroll
        for (int r = 0; r < 4; r++) Cf[(size_t)(rbase + r) * N + col] = acc[i][j][r] + bias[col];
      } else {
        if (col < 512) {                  // K projection -> Kb [b*NC+t][512]
          u16* Kb = (u16*)C0;
          #pragma unroll
          for (int r = 0; r < 4; r++) Kb[(size_t)(rbase + r) * 512 + col] = f2bf(acc[i][j][r]);
        } else {                          // V projection -> Vt, transposed + key-permuted
          u16* Vt = (u16*)C1;
          int hd = col - 512, h = hd >> 6, d = hd & 63;
          int bb = rbase >> 10, tl = rbase & 1023;
          int tbase = tl & ~63, a0 = tl & 63;          // a0 = quad*4-aligned key-local idx
          int pb = (a0 & 32) + ((a0 & 15) >> 2) * 8 + (((a0 >> 4) & 1) << 2);
          uint2 ov;
          ov.x = pack2(acc[i][j][0], acc[i][j][1]);
          ov.y = pack2(acc[i][j][2], acc[i][j][3]);
          *(uint2*)(Vt + ((size_t)(bb * NH + h) * DH + d) * NC + tbase + pb) = ov;
        }
      }
    }
  }
}

// ---------------- fused Q-proj + KV-proj (768 blocks = 3/CU) ----------------
__global__ __launch_bounds__(256, 3) void proj_all(const u16* __restrict__ xb, const u16* __restrict__ cb,
                                                   const u16* __restrict__ wqT, const u16* __restrict__ wkvT,
                                                   u16* __restrict__ Qb, u16* __restrict__ Kb,
                                                   u16* __restrict__ Vtb, float qscale) {
  __shared__ alignas(16) u16 Al[2][128][32];
  __shared__ alignas(16) u16 Bl[2][128][32];
  int bx = blockIdx.x;
  if (bx < 512) {  // Q projection: M=16384, N=512, K=512
    gemm_body<0>(xb, wqT, Qb, nullptr, nullptr, 512, 512, qscale, bx & 3, bx >> 2,
                 (u16*)Al, (u16*)Bl);
  } else {         // KV projection: M=4096, N=1024, K=768; K cols -> Kb, V cols -> Vt
    int bi = bx - 512;
    gemm_body<2>(cb, wkvT, Kb, Vtb, nullptr, 1024, 768, 1.0f, bi & 7, bi >> 3,
                 (u16*)Al, (u16*)Bl);
  }
}

// ---------------- output projection (fp32 out + bias) ----------------
__global__ __launch_bounds__(256, 2) void outproj(const u16* __restrict__ Ob, const u16* __restrict__ woT,
                                                  float* __restrict__ out, const float* __restrict__ bo) {
  __shared__ alignas(16) u16 Al[2][128][32];
  __shared__ alignas(16) u16 Bl[2][128][32];
  gemm_body<1>(Ob, woT, out, nullptr, bo, 512, 512, 1.0f, blockIdx.x, blockIdx.y,
               (u16*)Al, (u16*)Bl);
}

// ---------------- flash cross-attention: 32 q/wave, 64-key tiles, 4 blocks/CU ----------------
// S^T = K·Q^T; S^T C-layout packs in-register into the PV B-frag; V pre-permuted to match.
// O^T = V^T·P^T in C-layout (d contiguous per lane -> b64 stores).
// 256-thread blocks (4 waves x 32q = 128q), grid 1024 -> 4 blocks/CU = 16 waves/CU = 4/SIMD.
// Registers: aq 16 + oacc 32(AGPR) + temps ~= 100/wave -> fits the lb(256,4) 128-reg cap, no spill.
// K/V tiles [2][64][64] with XOR-chunk swizzle: conflict-free (R3-verified geometry).
__global__ __launch_bounds__(256, 4) void attn(const u16* __restrict__ Q, const u16* __restrict__ Kb,
                                               const u16* __restrict__ Vt, u16* __restrict__ O) {
  __shared__ alignas(16) u16 Kl[2][64][64];   // 16 KB
  __shared__ alignas(16) u16 Vl[2][64][64];   // 16 KB
  int qt = blockIdx.x, h = blockIdx.y, b = blockIdx.z;
  int tid = threadIdx.x, wave = tid >> 6, lane = tid & 63, quad = lane >> 4, l16 = lane & 15;
  int q0 = qt * 128 + wave * 32;
  int x7 = l16 & 7;

  // staging: K tile 512 chunks + V tile 512 chunks, 256 threads -> 2+2 g2l16 each.
  // seg s: row=s>>3, LDS chunk=s&7, global chunk=(s&7)^(row&7); rows 32-63 share kc (row&7 inv.)
  int kr = tid >> 3, kc = (tid & 7) ^ (kr & 7);
  const u16* kg = Kb + ((size_t)b * NC + kr) * 512 + h * DH + kc * 8;
  const u16* vg = Vt + ((size_t)(b * NH + h) * DH + kr) * NC + kc * 8;

#define ASTAGE(kt, buf) do { \
    const u16* kg_ = kg + (size_t)(kt) * 64 * 512; \
    const u16* vg_ = vg + (kt) * 64; \
    u16* kl_ = (u16*)Kl + (buf) * 4096; u16* vl_ = (u16*)Vl + (buf) * 4096; \
    g2l16(kg_,            kl_ + tid * 8); \
    g2l16(kg_ + 32 * 512, kl_ + (tid + 256) * 8); \
    g2l16(vg_,            vl_ + tid * 8); \
    g2l16(vg_ + 32 * NC,  vl_ + (tid + 256) * 8); } while (0)

  // Q B-frags (B[k=quad*8+j][n=l16]), in regs for the whole kernel: 2 n-subtiles x 2 k-chunks
  s8v aq[2][2];
  {
    const u16* Qp = Q + ((size_t)b * NQ + q0 + l16) * DI + h * DH + quad * 8;
    #pragma unroll
    for (int n = 0; n < 2; n++) {
      aq[n][0] = *(const s8v*)(Qp + (size_t)n * 16 * DI);
      aq[n][1] = *(const s8v*)(Qp + (size_t)n * 16 * DI + 32);
    }
  }
  f4v oacc[4][2];
  float lsum[2] = {0.f, 0.f};
  #pragma unroll
  for (int d = 0; d < 4; d++)
    #pragma unroll
    for (int n = 0; n < 2; n++) oacc[d][n] = (f4v){0.f, 0.f, 0.f, 0.f};

  ASTAGE(0, 0);
  for (int kt = 0; kt < NC / 64; ++kt) {
    int buf = kt & 1;
    __syncthreads();                       // drains prefetch; orders dbuf reuse
    if (kt + 1 < NC / 64) ASTAGE(kt + 1, buf ^ 1);
    const u16* kb = (const u16*)Kl + buf * 4096;
    const u16* vb = (const u16*)Vl + buf * 4096;

    #pragma unroll
    for (int c = 0; c < 2; c++) {          // 32-key chunk (m-subtiles 2c, 2c+1)
      f4v S[2][2];
      #pragma unroll
      for (int mi = 0; mi < 2; mi++)
        #pragma unroll
        for (int n = 0; n < 2; n++) S[mi][n] = (f4v){0.f, 0.f, 0.f, 0.f};
      #pragma unroll
      for (int cd = 0; cd < 2; cd++) {     // dh chunk
        int rA = 32 * c + l16;
        int ch = ((4 * cd + quad) ^ x7) * 8;
        s8v kf0 = *(const s8v*)(kb + rA * 64 + ch);
        s8v kf1 = *(const s8v*)(kb + (rA + 16) * 64 + ch);
        #pragma unroll
        for (int n = 0; n < 2; n++) {
          S[0][n] = __builtin_amdgcn_mfma_f32_16x16x32_bf16(kf0, aq[n][cd], S[0][n], 0, 0, 0);
          S[1][n] = __builtin_amdgcn_mfma_f32_16x16x32_bf16(kf1, aq[n][cd], S[1][n], 0, 0, 0);
        }
      }
      // exp2 + in-register pack into PV B-frag + row-sum accumulation
      s8v pf[2];
      #pragma unroll
      for (int n = 0; n < 2; n++) {
        float p00 = EXP2(S[0][n][0]), p01 = EXP2(S[0][n][1]), p02 = EXP2(S[0][n][2]), p03 = EXP2(S[0][n][3]);
        float p10 = EXP2(S[1][n][0]), p11 = EXP2(S[1][n][1]), p12 = EXP2(S[1][n][2]), p13 = EXP2(S[1][n][3]);
        lsum[n] += (p00 + p01) + (p02 + p03) + (p10 + p11) + (p12 + p13);
        union { u32 d[4]; s8v v; } u;
        u.d[0] = pack2(p00, p01); u.d[1] = pack2(p02, p03);
        u.d[2] = pack2(p10, p11); u.d[3] = pack2(p12, p13);
        pf[n] = u.v;
      }
      // O^T += V^T P^T
      #pragma unroll
      for (int d = 0; d < 4; d++) {
        int rV = d * 16 + l16;
        int ch = ((4 * c + quad) ^ x7) * 8;
        s8v vf = *(const s8v*)(vb + rV * 64 + ch);
        #pragma unroll
        for (int n = 0; n < 2; n++)
          oacc[d][n] = __builtin_amdgcn_mfma_f32_16x16x32_bf16(vf, pf[n], oacc[d][n], 0, 0, 0);
      }
    }
  }
#undef ASTAGE

  // reduce row sums across the 4 quads holding the same q (=l16 group)
  float inv[2];
  #pragma unroll
  for (int n = 0; n < 2; n++) {
    float s = lsum[n];
    s += __shfl_xor(s, 16); s += __shfl_xor(s, 32);
    inv[n] = 1.0f / s;
  }
  // write O[b][q][h*64+d]: lane holds 4 contiguous d per (dsub, n) -> b64 stores
  #pragma unroll
  for (int d = 0; d < 4; d++)
    #pragma unroll
    for (int n = 0; n < 2; n++) {
      int q = q0 + n * 16 + l16;
      uint2 ov;
      ov.x = pack2(oacc[d][n][0] * inv[n], oacc[d][n][1] * inv[n]);
      ov.y = pack2(oacc[d][n][2] * inv[n], oacc[d][n][3] * inv[n]);
      *(uint2*)(O + ((size_t)b * NQ + q) * DI + h * DH + d * 16 + quad * 4) = ov;
    }
}

extern "C" void kernel_launch(void* const* d_in, const int* in_sizes, int n_in,
                              void* d_out, int out_size, void* d_ws, size_t ws_size,
                              hipStream_t stream) {
  const float* x   = (const float*)d_in[0];
  const float* ctx = (const float*)d_in[1];
  const float* Wq  = (const float*)d_in[2];
  const float* Wk  = (const float*)d_in[3];
  const float* Wv  = (const float*)d_in[4];
  const float* Wo  = (const float*)d_in[5];
  const float* bo  = (const float*)d_in[6];
  float* out = (float*)d_out;

  u16* w    = (u16*)d_ws;                // workspace layout (bf16 elems)
  u16* xb   = w;                         // 8388608
  u16* cb   = xb   + 8388608;            // 3145728
  u16* wqT  = cb   + 3145728;            // 262144
  u16* wkvT = wqT  + 262144;             // 786432 (Wk^T rows 0-511, Wv^T rows 512-1023)
  u16* woT  = wkvT + 786432;             // 262144
  u16* Qb   = woT  + 262144;             // 8388608 (pre-scaled by 0.125*log2e)
  u16* Kbuf = Qb   + 8388608;            // 2097152 ([b*1024+t][512])
  u16* Vtb  = Kbuf + 2097152;            // 2097152 (key-permuted V^T)
  u16* Ob   = Vtb  + 2097152;            // 8388608

  const float qscale = 0.125f * 1.44269504f;  // softmax scale + log2(e) folded into Q

  prep<<<11648, 256, 0, stream>>>(x, ctx, Wq, Wk, Wv, Wo, xb, cb, wqT, wkvT, woT);
  proj_all<<<768, 256, 0, stream>>>(xb, cb, wqT, wkvT, Qb, Kbuf, Vtb, qscale);
  attn<<<dim3(32, 8, 4), 256, 0, stream>>>(Qb, Kbuf, Vtb, Ob);
  outproj<<<dim3(4, 128), 256, 0, stream>>>(Ob, woT, out, bo);
}